// Round 6
// baseline (172.508 us; speedup 1.0000x reference)
//
#include <hip/hip_runtime.h>

#define L_SIG 65536
#define NBATCH 16
#define M_BLK 8192            // positions per block (8 sub-tiles of 1024)
#define SCOPY 1288            // halfs per shifted signal copy (1280 data + 8 pad)

typedef _Float16 half8 __attribute__((ext_vector_type(8)));
typedef float f32x16 __attribute__((ext_vector_type(16)));

// ---------------------------------------------------------------------------
// CWT real part via MFMA — R6 DIAGNOSTIC ROUND.
//
// 5 rounds of theory-nulls (occupancy R1, LDS reads R3, store ordering R5)
// and cwt_mfma has NEVER appeared in the top-5 dispatch counters (all ~80us
// fills; kernel < 79us is invisible). This round: same R2 compute structure
// (the best measured, 142.7), but grid 1024 -> 128 blocks (M_BLK 1024->8192,
// staged as 8 sub-tiles with barriers). Half the CUs idle -> kernel ~2x its
// true duration -> surfaces in top-5 WITH its counter row:
//   WRITE_SIZE  (expect 131072 KB; >> => write amplification found)
//   FETCH_SIZE  (expect ~40-50 MB; >>134 MB => write-allocate RMW found)
//   SQ_LDS_BANK_CONFLICT (expect ~0; validates swizzle analysis)
//   hbm_gbps / MfmaUtil / VALUBusy / Occupancy for the real structure.
// Bytes-based counters are occupancy-independent. Revert grid next round.
//
// Math identical to R2: out[(n*32+s)*65536+h] = sum_k sig[n][h+k-128]*w[s][k]
// GEMM view: M=32 scales, N=positions, K=256 taps; A=wavelet (16 reg frags),
// B=signal (LDS, 8 shifted copies -> every read ds_read_b128-aligned).
// mfma_f32_32x32x16_f16: D col=lane&31=POSITION, row=scale
//   =(reg&3)+8*(reg>>2)+4*(lane>>5); direct coalesced stores (2x128B/inst).
// ---------------------------------------------------------------------------
__global__ __launch_bounds__(256, 3) void cwt_mfma(
        const float* __restrict__ sig,
        float* __restrict__ out) {

    __shared__ __align__(16) _Float16 w_lds[32 * 256];   // 16384 B
    __shared__ __align__(16) _Float16 s_lds[8 * SCOPY];  // 20608 B

    const int tid = threadIdx.x;
    const int n   = blockIdx.y;
    const int h0  = blockIdx.x * M_BLK;

    // ---- generate wavelet bank into w_lds (fp16, chunk-swizzled) ----
    {
        int o  = tid >> 3;                 // scale 0..31
        int k0 = (tid & 7) * 32;           // 32 taps per thread
        float scale = 1.0f + (float)o;
        float inv_s = 1.0f / scale;
        float pcoef = 37.699111843077518861f * inv_s * inv_s; // 2*pi*6/scale^2
        #pragma unroll
        for (int cc = 0; cc < 4; ++cc) {
            union { _Float16 h[8]; uint4 u4; } pk;
            #pragma unroll
            for (int j = 0; j < 8; ++j) {
                float km = (float)(k0 + cc * 8 + j) - 128.0f;
                float t = km * inv_s;
                float env = __expf(-0.5f * t * t);
                pk.h[j] = (_Float16)(env * __cosf(pcoef * km));
            }
            int cidx = (k0 >> 3) + cc;     // logical 16B chunk 0..31
            *(uint4*)&w_lds[o * 256 + ((cidx ^ (o & 7)) << 3)] = pk.u4;
        }
    }
    __syncthreads();

    const int w  = tid >> 6;
    const int l  = tid & 63;
    const int m5 = l & 31;     // A row (scale) / B col (position) / D col
    const int hk = l >> 5;     // k-half selector

    // ---- hoist all 16 wavelet A-fragments to registers (once) ----
    half8 af[16];
    #pragma unroll
    for (int ks = 0; ks < 16; ++ks) {
        int cidx = (ks << 1) + hk;
        af[ks] = *(const half8*)&w_lds[m5 * 256 + ((cidx ^ (m5 & 7)) << 3)];
    }

    const int bbase = (m5 & 7) * SCOPY + (m5 & 24) + (hk << 3) + w * 64;
    const size_t nsbase = ((size_t)(n * 32) << 16);
    const float* sp = sig + (size_t)n * L_SIG;

    #pragma unroll 1
    for (int st = 0; st < 8; ++st) {
        const int hs = h0 + st * 1024;

        // ---- stage 8 shifted fp16 copies of signal tile [hs-128, hs+1152) ----
        __syncthreads();                       // WAR: prior sub-tile reads done
        {
            const int base = hs - 128;
            if (hs >= 128 && hs + 1152 <= L_SIG) {
                #pragma unroll
                for (int c = 0; c < 8; ++c) {
                    for (int xi = tid; xi < 640; xi += 256) {
                        int x = xi * 2;
                        int e = base + c + x;
                        union { _Float16 h[2]; unsigned u; } p;
                        p.h[0] = (_Float16)sp[e];
                        p.h[1] = (_Float16)sp[e + 1];
                        *(unsigned*)&s_lds[c * SCOPY + x] = p.u;
                    }
                }
            } else {
                #pragma unroll
                for (int c = 0; c < 8; ++c) {
                    for (int xi = tid; xi < 640; xi += 256) {
                        int x = xi * 2;
                        int e = base + c + x;
                        float v0 = ((unsigned)e       < L_SIG) ? sp[e]     : 0.0f;
                        float v1 = ((unsigned)(e + 1) < L_SIG) ? sp[e + 1] : 0.0f;
                        union { _Float16 h[2]; unsigned u; } p;
                        p.h[0] = (_Float16)v0;
                        p.h[1] = (_Float16)v1;
                        *(unsigned*)&s_lds[c * SCOPY + x] = p.u;
                    }
                }
            }
        }
        __syncthreads();

        // ---- 4 chunks of 256 positions: R2 body verbatim ----
        #pragma unroll 1
        for (int c = 0; c < 4; ++c) {
            const _Float16* bp = &s_lds[bbase + c * 256];
            f32x16 acc0 = {};
            f32x16 acc1 = {};
            half8 b0 = *(const half8*)&bp[0];        // tile 0 (pos +0..31)
            half8 b1 = *(const half8*)&bp[32];       // tile 1 (pos +32..63)

            #pragma unroll
            for (int ks = 0; ks < 16; ++ks) {
                half8 nb0, nb1;
                if (ks < 15) {
                    nb0 = *(const half8*)&bp[(ks + 1) * 16];
                    nb1 = *(const half8*)&bp[(ks + 1) * 16 + 32];
                }
                acc0 = __builtin_amdgcn_mfma_f32_32x32x16_f16(af[ks], b0, acc0, 0, 0, 0);
                acc1 = __builtin_amdgcn_mfma_f32_32x32x16_f16(af[ks], b1, acc1, 0, 0, 0);
                b0 = nb0;
                b1 = nb1;
            }

            // direct coalesced stores: reg r -> scale row, 2x128B segments
            const size_t ob = nsbase + (size_t)(hs + w * 64 + c * 256);
            #pragma unroll
            for (int r = 0; r < 16; ++r) {
                size_t po = ob + ((size_t)((r & 3) + ((r >> 2) << 3) + (hk << 2)) << 16);
                out[po + m5]      = acc0[r];
                out[po + 32 + m5] = acc1[r];
            }
        }
    }
}

extern "C" void kernel_launch(void* const* d_in, const int* in_sizes, int n_in,
                              void* d_out, int out_size, void* d_ws, size_t ws_size,
                              hipStream_t stream) {
    const float* sig = (const float*)d_in[0];
    float* out = (float*)d_out;
    cwt_mfma<<<dim3(L_SIG / M_BLK, NBATCH), dim3(256), 0, stream>>>(sig, out);
}

// Round 7
// 148.335 us; speedup vs baseline: 1.1630x; 1.1630x over previous
//
#include <hip/hip_runtime.h>

#define L_SIG 65536
#define NBATCH 16
#define M_BLK 1024            // positions per block
#define SCOPY 1288            // halfs per shifted signal copy (1280 data + 8 pad)

typedef _Float16 half8 __attribute__((ext_vector_type(8)));
typedef float f32x16 __attribute__((ext_vector_type(16)));

// ---------------------------------------------------------------------------
// CWT real part via MFMA:
//   out[(n*32+s)*65536 + h] = sum_k sig[n][h+k-128] * w[s][k]
//
// R6 diagnostic results: WRITE_SIZE exactly ideal (no amplification; R5's
// store-locality theory dead), VGPR_Count=84 (register file 2/3 idle),
// serial rate 10.2us/sub-tile vs ~2.5us issue model, and co-residency makes
// per-sub-tile time WORSE (13us at 3 blocks/CU) -> per-wave latency stalls
// that TLP cannot hide: dependent-MFMA chains, per-chunk store drains
// (vmcnt before acc reg reuse), staging barrier.
//
// R7: spend registers on ILP. 4 accumulators/wave (4 position-tiles of 32,
// 128 pos/wave), M_BLK=1024 -> 2 chunks of 512:
//   - 4 independent MFMA chains (was 2): dep-latency per chunk halves
//   - store-drain boundaries 4 -> 2
//   - B-ring of 8 with shift identity (tile t, k-step ks -> frag ks+2t):
//     22 ds_read_b128/chunk for 4 tiles (44/sub-tile vs 128 in R2 body)
//   - chunk loop fully unrolled: fresh acc regs for chunk 1 -> chunk 0's
//     store drain overlaps chunk 1 compute (~240 VGPR, fits 2 waves/SIMD;
//     R1 proved occupancy >2 blocks/CU is not a limiter)
//
// GEMM view: M=32 scales, N=positions, K=256 taps; A=wavelet hoisted to 16
// reg frags; B=signal from LDS (8 shifted copies, copy=pos&7, every read a
// 16B-aligned ds_read_b128; w*128/c*512 offsets are bank-rotation-neutral).
// mfma_f32_32x32x16_f16: D col=lane&31=POSITION, row=scale
//   =(reg&3)+8*(reg>>2)+4*(lane>>5); direct coalesced stores (2x128B/inst).
// ---------------------------------------------------------------------------
__global__ __launch_bounds__(256, 2) void cwt_mfma(
        const float* __restrict__ sig,
        float* __restrict__ out) {

    __shared__ __align__(16) _Float16 w_lds[32 * 256];   // 16384 B
    __shared__ __align__(16) _Float16 s_lds[8 * SCOPY];  // 20608 B

    const int tid = threadIdx.x;
    const int n   = blockIdx.y;
    const int h0  = blockIdx.x * M_BLK;

    // ---- generate wavelet bank into w_lds (fp16, chunk-swizzled) ----
    {
        int o  = tid >> 3;                 // scale 0..31
        int k0 = (tid & 7) * 32;           // 32 taps per thread
        float scale = 1.0f + (float)o;
        float inv_s = 1.0f / scale;
        float pcoef = 37.699111843077518861f * inv_s * inv_s; // 2*pi*6/scale^2
        #pragma unroll
        for (int cc = 0; cc < 4; ++cc) {
            union { _Float16 h[8]; uint4 u4; } pk;
            #pragma unroll
            for (int j = 0; j < 8; ++j) {
                float km = (float)(k0 + cc * 8 + j) - 128.0f;
                float t = km * inv_s;
                float env = __expf(-0.5f * t * t);
                pk.h[j] = (_Float16)(env * __cosf(pcoef * km));
            }
            int cidx = (k0 >> 3) + cc;     // logical 16B chunk 0..31
            *(uint4*)&w_lds[o * 256 + ((cidx ^ (o & 7)) << 3)] = pk.u4;
        }
    }

    // ---- stage 8 shifted fp16 copies of signal tile [h0-128, h0+1152) ----
    {
        const float* sp = sig + (size_t)n * L_SIG;
        const int base = h0 - 128;
        if (h0 >= 128 && h0 + 1152 <= L_SIG) {
            #pragma unroll
            for (int c = 0; c < 8; ++c) {
                for (int xi = tid; xi < 640; xi += 256) {
                    int x = xi * 2;
                    int e = base + c + x;
                    union { _Float16 h[2]; unsigned u; } p;
                    p.h[0] = (_Float16)sp[e];
                    p.h[1] = (_Float16)sp[e + 1];
                    *(unsigned*)&s_lds[c * SCOPY + x] = p.u;
                }
            }
        } else {
            #pragma unroll
            for (int c = 0; c < 8; ++c) {
                for (int xi = tid; xi < 640; xi += 256) {
                    int x = xi * 2;
                    int e = base + c + x;
                    float v0 = ((unsigned)e       < L_SIG) ? sp[e]     : 0.0f;
                    float v1 = ((unsigned)(e + 1) < L_SIG) ? sp[e + 1] : 0.0f;
                    union { _Float16 h[2]; unsigned u; } p;
                    p.h[0] = (_Float16)v0;
                    p.h[1] = (_Float16)v1;
                    *(unsigned*)&s_lds[c * SCOPY + x] = p.u;
                }
            }
        }
    }
    __syncthreads();

    const int w  = tid >> 6;
    const int l  = tid & 63;
    const int m5 = l & 31;     // A row (scale) / B col (position) / D col
    const int hk = l >> 5;     // k-half selector

    // ---- hoist all 16 wavelet A-fragments to registers ----
    half8 af[16];
    #pragma unroll
    for (int ks = 0; ks < 16; ++ks) {
        int cidx = (ks << 1) + hk;
        af[ks] = *(const half8*)&w_lds[m5 * 256 + ((cidx ^ (m5 & 7)) << 3)];
    }

    // B-read base: copy (m5&7), x = w*128 + (m5&24) + hk*8 (+ c*512 + f*16).
    // All terms multiple of 8 halfs -> aligned ds_read_b128.
    const int bbase = (m5 & 7) * SCOPY + (m5 & 24) + (hk << 3) + w * 128;
    const size_t obase = ((size_t)(n * 32) << 16) + (size_t)(h0 + w * 128);

    // Ring invariant: b[j] holds frag f == j (mod 8); tile t at k-step ks
    // consumes frag ks+2t (positions +32t = +2t k-steps of 16 taps).
    #pragma unroll
    for (int c = 0; c < 2; ++c) {
        const _Float16* bp = &s_lds[bbase + c * 512];
        f32x16 acc0 = {};
        f32x16 acc1 = {};
        f32x16 acc2 = {};
        f32x16 acc3 = {};
        half8 b[8];
        #pragma unroll
        for (int u = 0; u < 8; ++u)
            b[u] = *(const half8*)&bp[u * 16];

        #pragma unroll
        for (int ks = 0; ks < 16; ++ks) {
            acc0 = __builtin_amdgcn_mfma_f32_32x32x16_f16(af[ks], b[ks & 7],
                                                          acc0, 0, 0, 0);
            acc1 = __builtin_amdgcn_mfma_f32_32x32x16_f16(af[ks], b[(ks + 2) & 7],
                                                          acc1, 0, 0, 0);
            acc2 = __builtin_amdgcn_mfma_f32_32x32x16_f16(af[ks], b[(ks + 4) & 7],
                                                          acc2, 0, 0, 0);
            acc3 = __builtin_amdgcn_mfma_f32_32x32x16_f16(af[ks], b[(ks + 6) & 7],
                                                          acc3, 0, 0, 0);
            if (ks < 14)
                b[ks & 7] = *(const half8*)&bp[(ks + 8) * 16];  // frag ks+8
        }

        // ---- direct coalesced stores from accumulators ----
        // reg r -> scale row (r&3)+8*(r>>2)+4*hk; tile t -> positions +32t;
        // each store = 2 x 128B contiguous segments.
        const size_t ob = obase + (size_t)(c * 512);
        #pragma unroll
        for (int r = 0; r < 16; ++r) {
            size_t po = ob + ((size_t)((r & 3) + ((r >> 2) << 3) + (hk << 2)) << 16);
            out[po + m5]      = acc0[r];
            out[po + 32 + m5] = acc1[r];
            out[po + 64 + m5] = acc2[r];
            out[po + 96 + m5] = acc3[r];
        }
    }
}

extern "C" void kernel_launch(void* const* d_in, const int* in_sizes, int n_in,
                              void* d_out, int out_size, void* d_ws, size_t ws_size,
                              hipStream_t stream) {
    const float* sig = (const float*)d_in[0];
    float* out = (float*)d_out;
    cwt_mfma<<<dim3(L_SIG / M_BLK, NBATCH), dim3(256), 0, stream>>>(sig, out);
}